// Round 5
// baseline (231.693 us; speedup 1.0000x reference)
//
#include <hip/hip_runtime.h>
#include <hip/hip_fp16.h>

#define S   128
#define SS  (S * S)
#define PW  136            // padded dim (x,y,z): 128 + 2*PAD
#define PWH (PW * PW)
#define PAD 4              // zero border; absorbs the +/-2-step clip widening

__device__ __forceinline__ float fetch_padded(const float* __restrict__ vol,
                                              int x, int y, int z) {
    const int xm = x - PAD, ym = y - PAD, zm = z - PAD;
    if (((unsigned)xm < 128u) & ((unsigned)ym < 128u) & ((unsigned)zm < 128u))
        return vol[(zm * S + ym) * S + xm];
    return 0.0f;
}

// ---------------------------------------------------------------------------
// Prep A: fp32 volume -> pair-interleaved padded fp16 volume.
// pp[m] = half2( v[m], v[m+1] ) over the padded 136^3 linear index.
// Every trilinear x-row (taps xi, xi+1) becomes ONE aligned dword load.
// ---------------------------------------------------------------------------
__global__ __launch_bounds__(256) void pad_pair_kernel(
    const float* __restrict__ vol, unsigned* __restrict__ pp)
{
    const int t = blockIdx.x * 256 + threadIdx.x;    // [0, PW^3)
    const int x = t % PW;
    const int r = t / PW;
    const int y = r % PW;
    const int z = r / PW;

    const float v0 = fetch_padded(vol, x, y, z);
    const float v1 = (x + 1 < PW) ? fetch_padded(vol, x + 1, y, z) : 0.0f;
    const __half2 h = __floats2half2_rn(v0, v1);
    pp[t] = *(const unsigned*)&h;
}

// ---------------------------------------------------------------------------
// Prep B (fallback tier): fp32 volume -> plain padded fp16 volume.
// ---------------------------------------------------------------------------
__global__ __launch_bounds__(256) void pad_half_kernel(
    const float* __restrict__ vol, __half* __restrict__ pv)
{
    const int t = blockIdx.x * 256 + threadIdx.x;    // [0, PW^3)
    const int x = t % PW;
    const int r = t / PW;
    const int y = r % PW;
    const int z = r / PW;
    pv[t] = __float2half(fetch_padded(vol, x, y, z));
}

// ---------------------------------------------------------------------------
// Ray setup. Padded coords; contribution possible only in (PAD-1, PAD+128)
// = (3,132) per coordinate. k-range widened by up to 2 steps each side; with
// |u|<=1 the position then stays within (1-eps, 134+eps) -> indices [0,134],
// +1 taps <= 135 = PW-1. Always in-bounds.
// ---------------------------------------------------------------------------
struct Ray {
    float ix0, iy0, iz0, ux, uy, uz;
    int kmin, kmax;
};

__device__ __forceinline__ Ray make_ray(const float* __restrict__ rot,
                                        int b, int i, int j, int seg) {
    const float* Rb = rot + b * 9;
    const float r00 = Rb[0], r01 = Rb[1], r02 = Rb[2];
    const float r10 = Rb[3], r11 = Rb[4], r12 = Rb[5];
    const float r20 = Rb[6], r21 = Rb[7], r22 = Rb[8];

    const float step = 2.0f / 127.0f;
    const float li = -1.0f + step * (float)i;
    const float lj = -1.0f + step * (float)j;

    Ray ry;
    ry.ix0 = (lj * r00 + li * r10 - r20 + 1.0f) * 63.5f + (float)PAD;
    ry.iy0 = (lj * r01 + li * r11 - r21 + 1.0f) * 63.5f + (float)PAD;
    ry.iz0 = (lj * r02 + li * r12 - r22 + 1.0f) * 63.5f + (float)PAD;
    ry.ux = r20; ry.uy = r21; ry.uz = r22;

    float klo = 0.0f, khi = 127.0f;
    const float lo = (float)(PAD - 1), hi = (float)(PAD + 128);
    if (fabsf(ry.ux) > 1e-7f) {
        float a = (lo - ry.ix0) / ry.ux, c = (hi - ry.ix0) / ry.ux;
        klo = fmaxf(klo, fminf(a, c)); khi = fminf(khi, fmaxf(a, c));
    } else if (ry.ix0 <= lo || ry.ix0 >= hi) { klo = 1e9f; khi = -1e9f; }
    if (fabsf(ry.uy) > 1e-7f) {
        float a = (lo - ry.iy0) / ry.uy, c = (hi - ry.iy0) / ry.uy;
        klo = fmaxf(klo, fminf(a, c)); khi = fminf(khi, fmaxf(a, c));
    } else if (ry.iy0 <= lo || ry.iy0 >= hi) { klo = 1e9f; khi = -1e9f; }
    if (fabsf(ry.uz) > 1e-7f) {
        float a = (lo - ry.iz0) / ry.uz, c = (hi - ry.iz0) / ry.uz;
        klo = fmaxf(klo, fminf(a, c)); khi = fminf(khi, fmaxf(a, c));
    } else if (ry.iz0 <= lo || ry.iz0 >= hi) { klo = 1e9f; khi = -1e9f; }

    ry.kmin = seg * 64; ry.kmax = seg * 64 + 63;
    if (klo <= khi) {
        // Widen by 1 integer step each side; pad zeros absorb the slack.
        ry.kmin = max(ry.kmin, (int)floorf(klo) - 1);
        ry.kmax = min(ry.kmax, (int)ceilf(khi) + 1);
    } else {
        ry.kmax = ry.kmin - 1;
    }
    return ry;
}

// ---------------------------------------------------------------------------
// Main (pair layout): one thread per (pixel, k-segment), 8x8 pixels per wave.
// 4 aligned dword gathers per trilinear tap.
// ---------------------------------------------------------------------------
__global__ __launch_bounds__(256) void projector_pair(
    const float* __restrict__ rot,     // [16,3,3]
    const unsigned* __restrict__ pp,   // [136^3] pair-interleaved fp16
    float* __restrict__ out)           // [16,1,128,128], pre-zeroed
{
    // Grid: 2048 = seg(2) x b(16) x tile(64)
    const int blk  = blockIdx.x;
    const int seg  = blk >> 10;
    const int rest = blk & 1023;
    const int b    = rest >> 6;
    const int tile = rest & 63;          // 8x8 tiles of 16x16 pixels
    const int tY   = tile >> 3, tX = tile & 7;

    const int wave = threadIdx.x >> 6;   // 2x2 waves inside block
    const int lane = threadIdx.x & 63;   // 8x8 pixels inside wave
    const int i = tY * 16 + (wave >> 1) * 8 + (lane >> 3);
    const int j = tX * 16 + (wave & 1) * 8 + (lane & 7);

    const Ray ry = make_ray(rot, b, i, j, seg);

    float acc = 0.0f;
    for (int k = ry.kmin; k <= ry.kmax; ++k) {
        const float kk = (float)k;
        const float ix = fmaf(kk, ry.ux, ry.ix0);
        const float iy = fmaf(kk, ry.uy, ry.iy0);
        const float iz = fmaf(kk, ry.uz, ry.iz0);

        const float xf = floorf(ix), yf = floorf(iy), zf = floorf(iz);
        const float fx = ix - xf, fy = iy - yf, fz = iz - zf;
        const int xi = (int)xf, yi = (int)yf, zi = (int)zf;

        const int base = (zi * PW + yi) * PW + xi;
        const unsigned q00 = pp[base];
        const unsigned q01 = pp[base + PW];
        const unsigned q10 = pp[base + PWH];
        const unsigned q11 = pp[base + PWH + PW];

        const float2 f00 = __half22float2(*(const __half2*)&q00);
        const float2 f01 = __half22float2(*(const __half2*)&q01);
        const float2 f10 = __half22float2(*(const __half2*)&q10);
        const float2 f11 = __half22float2(*(const __half2*)&q11);

        const float c00 = fmaf(fx, f00.y - f00.x, f00.x);
        const float c01 = fmaf(fx, f01.y - f01.x, f01.x);
        const float c10 = fmaf(fx, f10.y - f10.x, f10.x);
        const float c11 = fmaf(fx, f11.y - f11.x, f11.x);
        const float c0  = fmaf(fy, c01 - c00, c00);
        const float c1  = fmaf(fy, c11 - c10, c10);
        acc += fmaf(fz, c1 - c0, c0);
    }

    // 2 commutative fp32 adds per address -> deterministic.
    atomicAdd(&out[(b << 14) + (i << 7) + j], acc);
}

// ---------------------------------------------------------------------------
// Fallback tier 2 (plain padded fp16, scalar loads).
// ---------------------------------------------------------------------------
__global__ __launch_bounds__(256) void projector_halfsc(
    const float* __restrict__ rot, const __half* __restrict__ pv,
    float* __restrict__ out)
{
    const int blk  = blockIdx.x;
    const int seg  = blk >> 10;
    const int rest = blk & 1023;
    const int b    = rest >> 6;
    const int tile = rest & 63;
    const int tY   = tile >> 3, tX = tile & 7;
    const int wave = threadIdx.x >> 6;
    const int lane = threadIdx.x & 63;
    const int i = tY * 16 + (wave >> 1) * 8 + (lane >> 3);
    const int j = tX * 16 + (wave & 1) * 8 + (lane & 7);

    const Ray ry = make_ray(rot, b, i, j, seg);

    float acc = 0.0f;
    for (int k = ry.kmin; k <= ry.kmax; ++k) {
        const float kk = (float)k;
        const float ix = fmaf(kk, ry.ux, ry.ix0);
        const float iy = fmaf(kk, ry.uy, ry.iy0);
        const float iz = fmaf(kk, ry.uz, ry.iz0);
        const float xf = floorf(ix), yf = floorf(iy), zf = floorf(iz);
        const float fx = ix - xf, fy = iy - yf, fz = iz - zf;
        const int xi = (int)xf, yi = (int)yf, zi = (int)zf;
        const __half* p = pv + (zi * PW + yi) * PW + xi;
        const float v000 = __half2float(p[0]),        v001 = __half2float(p[1]);
        const float v010 = __half2float(p[PW]),       v011 = __half2float(p[PW + 1]);
        const float v100 = __half2float(p[PWH]),      v101 = __half2float(p[PWH + 1]);
        const float v110 = __half2float(p[PWH + PW]), v111 = __half2float(p[PWH + PW + 1]);
        const float c00 = fmaf(fx, v001 - v000, v000);
        const float c01 = fmaf(fx, v011 - v010, v010);
        const float c10 = fmaf(fx, v101 - v100, v100);
        const float c11 = fmaf(fx, v111 - v110, v110);
        const float c0  = fmaf(fy, c01 - c00, c00);
        const float c1  = fmaf(fy, c11 - c10, c10);
        acc += fmaf(fz, c1 - c0, c0);
    }
    atomicAdd(&out[(b << 14) + (i << 7) + j], acc);
}

// ---------------------------------------------------------------------------
// Fallback tier 3: direct fp32, boundary-checked, no workspace (R1 kernel).
// ---------------------------------------------------------------------------
__global__ __launch_bounds__(256) void projector_f32(
    const float* __restrict__ rot, const float* __restrict__ vol,
    float* __restrict__ out)
{
    const int pix = blockIdx.x * 256 + threadIdx.x;
    const int b = pix >> 14, rem = pix & 16383;
    const int i = rem >> 7, j = rem & 127;
    const float* Rb = rot + b * 9;
    const float step = 2.0f / 127.0f;
    const float li = -1.0f + step * (float)i;
    const float lj = -1.0f + step * (float)j;
    const float ix0 = (lj * Rb[0] + li * Rb[3] - Rb[6] + 1.0f) * 63.5f;
    const float iy0 = (lj * Rb[1] + li * Rb[4] - Rb[7] + 1.0f) * 63.5f;
    const float iz0 = (lj * Rb[2] + li * Rb[5] - Rb[8] + 1.0f) * 63.5f;
    const float ux = Rb[6], uy = Rb[7], uz = Rb[8];
    float acc = 0.0f;
    for (int k = 0; k < 128; ++k) {
        const float kk = (float)k;
        const float ix = fmaf(kk, ux, ix0), iy = fmaf(kk, uy, iy0), iz = fmaf(kk, uz, iz0);
        const float xf = floorf(ix), yf = floorf(iy), zf = floorf(iz);
        const float fx = ix - xf, fy = iy - yf, fz = iz - zf;
        const int x0 = (int)xf, y0 = (int)yf, z0 = (int)zf;
        const int x1 = x0 + 1, y1 = y0 + 1, z1 = z0 + 1;
        const bool vx0 = (unsigned)x0 < 128u, vx1 = (unsigned)x1 < 128u;
        const bool vy0 = (unsigned)y0 < 128u, vy1 = (unsigned)y1 < 128u;
        const bool vz0 = (unsigned)z0 < 128u, vz1 = (unsigned)z1 < 128u;
        const float v000 = (vx0 && vy0 && vz0) ? vol[(z0 * S + y0) * S + x0] : 0.0f;
        const float v001 = (vx1 && vy0 && vz0) ? vol[(z0 * S + y0) * S + x1] : 0.0f;
        const float v010 = (vx0 && vy1 && vz0) ? vol[(z0 * S + y1) * S + x0] : 0.0f;
        const float v011 = (vx1 && vy1 && vz0) ? vol[(z0 * S + y1) * S + x1] : 0.0f;
        const float v100 = (vx0 && vy0 && vz1) ? vol[(z1 * S + y0) * S + x0] : 0.0f;
        const float v101 = (vx1 && vy0 && vz1) ? vol[(z1 * S + y0) * S + x1] : 0.0f;
        const float v110 = (vx0 && vy1 && vz1) ? vol[(z1 * S + y1) * S + x0] : 0.0f;
        const float v111 = (vx1 && vy1 && vz1) ? vol[(z1 * S + y1) * S + x1] : 0.0f;
        const float c00 = v000 + fx * (v001 - v000);
        const float c01 = v010 + fx * (v011 - v010);
        const float c10 = v100 + fx * (v101 - v100);
        const float c11 = v110 + fx * (v111 - v110);
        const float c0 = c00 + fy * (c01 - c00);
        const float c1 = c10 + fy * (c11 - c10);
        acc += c0 + fz * (c1 - c0);
    }
    out[pix] = acc;
}

extern "C" void kernel_launch(void* const* d_in, const int* in_sizes, int n_in,
                              void* d_out, int out_size, void* d_ws, size_t ws_size,
                              hipStream_t stream) {
    const float* rot = (const float*)d_in[0];   // [16,3,3]
    const float* vol = (const float*)d_in[1];   // [128^3] fp32
    float* out = (float*)d_out;                 // [16*128*128]

    const int    nvox      = PW * PW * PW;                    // 2,515,456
    const size_t need_pair = (size_t)nvox * sizeof(unsigned); // ~10.06 MB
    const size_t need_half = (size_t)nvox * sizeof(__half);   // ~5.03 MB

    if (ws_size >= need_pair) {
        unsigned* pp = (unsigned*)d_ws;
        hipMemsetAsync(out, 0, (size_t)out_size * sizeof(float), stream);
        pad_pair_kernel<<<nvox / 256, 256, 0, stream>>>(vol, pp);
        projector_pair<<<2048, 256, 0, stream>>>(rot, pp, out);
    } else if (ws_size >= need_half) {
        __half* pv = (__half*)d_ws;
        hipMemsetAsync(out, 0, (size_t)out_size * sizeof(float), stream);
        pad_half_kernel<<<nvox / 256, 256, 0, stream>>>(vol, pv);
        projector_halfsc<<<2048, 256, 0, stream>>>(rot, pv, out);
    } else {
        projector_f32<<<(16 * SS) / 256, 256, 0, stream>>>(rot, vol, out);
    }
}

// Round 6
// 161.434 us; speedup vs baseline: 1.4352x; 1.4352x over previous
//
#include <hip/hip_runtime.h>
#include <hip/hip_fp16.h>

#define S    128
#define SS   (S * S)
#define PW   136             // padded dim: 128 + 2*PAD
#define PWH  (PW * PW)
#define PAD  4               // absorbs +/-2-step clip widening (proven in R5)
#define VOXN (PW * PW * PW)  // 2,515,456 (divisible by 256)

__device__ __forceinline__ float fetch_padded(const float* __restrict__ vol,
                                              int x, int y, int z) {
    const int xm = x - PAD, ym = y - PAD, zm = z - PAD;
    if (((unsigned)xm < 128u) & ((unsigned)ym < 128u) & ((unsigned)zm < 128u))
        return vol[(zm * S + ym) * S + xm];
    return 0.0f;
}

// ---------------------------------------------------------------------------
// Prep: builds ncopies axis-permuted, zero-padded fp16 copies of the volume.
// Copy cp, local flat index t = (a*PW + b)*PW + c stores:
//   cp=0: vol(x=c, y=b, z=a)   (standard: x fast)
//   cp=1: vol(x=b, y=c, z=a)   (y fast)
//   cp=2: vol(x=b, y=a, z=c)   (z fast)
// Writes are fully coalesced; reads are strided gathers of the small fp32
// volume (L2-resident) - negligible.
// ---------------------------------------------------------------------------
__global__ __launch_bounds__(256) void pad_perm_kernel(
    const float* __restrict__ vol, __half* __restrict__ pv)
{
    int t = blockIdx.x * 256 + threadIdx.x;     // [0, ncopies*VOXN)
    const int cp = t / VOXN;
    t -= cp * VOXN;
    const int c = t % PW;
    const int r = t / PW;
    const int bq = r % PW;
    const int a = r / PW;

    int x, y, z;
    if (cp == 0)      { x = c;  y = bq; z = a; }
    else if (cp == 1) { x = bq; y = c;  z = a; }
    else              { x = bq; y = a;  z = c; }

    pv[cp * VOXN + (a * PW + bq) * PW + c] = __float2half(fetch_padded(vol, x, y, z));
}

// ---------------------------------------------------------------------------
// Ray setup (original axes). Clip window (PAD-1, PAD+128) = (3,132); widening
// of <=2 steps keeps coords in (1,134) -> all 8 taps in [0,135]. In-bounds.
// ---------------------------------------------------------------------------
struct Ray {
    float ix0, iy0, iz0, ux, uy, uz;
    int kmin, kmax;
};

__device__ __forceinline__ Ray make_ray(const float* __restrict__ rot,
                                        int b, int i, int j, int seg) {
    const float* Rb = rot + b * 9;
    const float r00 = Rb[0], r01 = Rb[1], r02 = Rb[2];
    const float r10 = Rb[3], r11 = Rb[4], r12 = Rb[5];
    const float r20 = Rb[6], r21 = Rb[7], r22 = Rb[8];

    const float step = 2.0f / 127.0f;
    const float li = -1.0f + step * (float)i;
    const float lj = -1.0f + step * (float)j;

    Ray ry;
    ry.ix0 = (lj * r00 + li * r10 - r20 + 1.0f) * 63.5f + (float)PAD;
    ry.iy0 = (lj * r01 + li * r11 - r21 + 1.0f) * 63.5f + (float)PAD;
    ry.iz0 = (lj * r02 + li * r12 - r22 + 1.0f) * 63.5f + (float)PAD;
    ry.ux = r20; ry.uy = r21; ry.uz = r22;

    float klo = 0.0f, khi = 127.0f;
    const float lo = (float)(PAD - 1), hi = (float)(PAD + 128);
    if (fabsf(ry.ux) > 1e-7f) {
        float a = (lo - ry.ix0) / ry.ux, c = (hi - ry.ix0) / ry.ux;
        klo = fmaxf(klo, fminf(a, c)); khi = fminf(khi, fmaxf(a, c));
    } else if (ry.ix0 <= lo || ry.ix0 >= hi) { klo = 1e9f; khi = -1e9f; }
    if (fabsf(ry.uy) > 1e-7f) {
        float a = (lo - ry.iy0) / ry.uy, c = (hi - ry.iy0) / ry.uy;
        klo = fmaxf(klo, fminf(a, c)); khi = fminf(khi, fmaxf(a, c));
    } else if (ry.iy0 <= lo || ry.iy0 >= hi) { klo = 1e9f; khi = -1e9f; }
    if (fabsf(ry.uz) > 1e-7f) {
        float a = (lo - ry.iz0) / ry.uz, c = (hi - ry.iz0) / ry.uz;
        klo = fmaxf(klo, fminf(a, c)); khi = fminf(khi, fmaxf(a, c));
    } else if (ry.iz0 <= lo || ry.iz0 >= hi) { klo = 1e9f; khi = -1e9f; }

    ry.kmin = seg * 32; ry.kmax = seg * 32 + 31;   // split-k 4
    if (klo <= khi) {
        ry.kmin = max(ry.kmin, (int)floorf(klo) - 1);
        ry.kmax = min(ry.kmax, (int)ceilf(khi) + 1);
    } else {
        ry.kmax = ry.kmin - 1;
    }
    return ry;
}

// ---------------------------------------------------------------------------
// Main: one thread per (pixel, k-segment); 8x8 pixels per wave.
// Per batch, gathers from the permuted copy whose fast axis is most
// perpendicular to the ray direction (minimizes cache lines per wave-gather).
// NC = number of volume copies available (3 or 1).
// ---------------------------------------------------------------------------
template <int NC>
__global__ __launch_bounds__(256) void projector_perm(
    const float* __restrict__ rot,   // [16,3,3]
    const __half* __restrict__ pv,   // [NC][136^3] permuted padded fp16
    float* __restrict__ out)         // [16,1,128,128], pre-zeroed
{
    // Grid 4096 = b(16, outermost: clusters L2 hot set) x seg(4) x tile(64)
    const int blk  = blockIdx.x;
    const int b    = blk >> 8;
    const int seg  = (blk >> 6) & 3;
    const int tile = blk & 63;
    const int tY   = tile >> 3, tX = tile & 7;

    const int wave = threadIdx.x >> 6;   // 2x2 waves inside block
    const int lane = threadIdx.x & 63;   // 8x8 pixels inside wave
    const int i = tY * 16 + (wave >> 1) * 8 + (lane >> 3);
    const int j = tX * 16 + (wave & 1) * 8 + (lane & 7);

    const Ray ry = make_ray(rot, b, i, j, seg);

    // Pick fast axis = argmin |u_axis|; permute ray into (x'=fast, y'=+PW,
    // z'=+PWH) space matching copy sel's layout.
    int sel = 0;
    float px0 = ry.ix0, py0 = ry.iy0, pz0 = ry.iz0;
    float pux = ry.ux,  puy = ry.uy,  puz = ry.uz;
    if (NC == 3) {
        const float ax = fabsf(ry.ux), ay = fabsf(ry.uy), az = fabsf(ry.uz);
        sel = (ax <= ay && ax <= az) ? 0 : ((ay <= az) ? 1 : 2);
        if (sel == 1) {        // copy1: flat=(z*PW+x)*PW+y
            px0 = ry.iy0; py0 = ry.ix0;
            pux = ry.uy;  puy = ry.ux;
        } else if (sel == 2) { // copy2: flat=(y*PW+x)*PW+z
            px0 = ry.iz0; py0 = ry.ix0; pz0 = ry.iy0;
            pux = ry.uz;  puy = ry.ux;  puz = ry.uy;
        }
    }
    const __half* __restrict__ vol = pv + sel * VOXN;

    float acc = 0.0f;
    #pragma unroll 2
    for (int k = ry.kmin; k <= ry.kmax; ++k) {
        const float kk = (float)k;
        const float ix = fmaf(kk, pux, px0);
        const float iy = fmaf(kk, puy, py0);
        const float iz = fmaf(kk, puz, pz0);

        const float xf = floorf(ix), yf = floorf(iy), zf = floorf(iz);
        const float fx = ix - xf, fy = iy - yf, fz = iz - zf;
        const int xi = (int)xf, yi = (int)yf, zi = (int)zf;

        const __half* p = vol + (zi * PW + yi) * PW + xi;
        const float v000 = __half2float(p[0]),        v001 = __half2float(p[1]);
        const float v010 = __half2float(p[PW]),       v011 = __half2float(p[PW + 1]);
        const float v100 = __half2float(p[PWH]),      v101 = __half2float(p[PWH + 1]);
        const float v110 = __half2float(p[PWH + PW]), v111 = __half2float(p[PWH + PW + 1]);

        const float c00 = fmaf(fx, v001 - v000, v000);
        const float c01 = fmaf(fx, v011 - v010, v010);
        const float c10 = fmaf(fx, v101 - v100, v100);
        const float c11 = fmaf(fx, v111 - v110, v110);
        const float c0  = fmaf(fy, c01 - c00, c00);
        const float c1  = fmaf(fy, c11 - c10, c10);
        acc += fmaf(fz, c1 - c0, c0);
    }

    // 4 commutative fp32 adds per address; rounding jitter << threshold.
    atomicAdd(&out[(b << 14) + (i << 7) + j], acc);
}

// ---------------------------------------------------------------------------
// Fallback: direct fp32, boundary-checked, no workspace (R1 kernel, passed).
// ---------------------------------------------------------------------------
__global__ __launch_bounds__(256) void projector_f32(
    const float* __restrict__ rot, const float* __restrict__ vol,
    float* __restrict__ out)
{
    const int pix = blockIdx.x * 256 + threadIdx.x;
    const int b = pix >> 14, rem = pix & 16383;
    const int i = rem >> 7, j = rem & 127;
    const float* Rb = rot + b * 9;
    const float step = 2.0f / 127.0f;
    const float li = -1.0f + step * (float)i;
    const float lj = -1.0f + step * (float)j;
    const float ix0 = (lj * Rb[0] + li * Rb[3] - Rb[6] + 1.0f) * 63.5f;
    const float iy0 = (lj * Rb[1] + li * Rb[4] - Rb[7] + 1.0f) * 63.5f;
    const float iz0 = (lj * Rb[2] + li * Rb[5] - Rb[8] + 1.0f) * 63.5f;
    const float ux = Rb[6], uy = Rb[7], uz = Rb[8];
    float acc = 0.0f;
    for (int k = 0; k < 128; ++k) {
        const float kk = (float)k;
        const float ix = fmaf(kk, ux, ix0), iy = fmaf(kk, uy, iy0), iz = fmaf(kk, uz, iz0);
        const float xf = floorf(ix), yf = floorf(iy), zf = floorf(iz);
        const float fx = ix - xf, fy = iy - yf, fz = iz - zf;
        const int x0 = (int)xf, y0 = (int)yf, z0 = (int)zf;
        const int x1 = x0 + 1, y1 = y0 + 1, z1 = z0 + 1;
        const bool vx0 = (unsigned)x0 < 128u, vx1 = (unsigned)x1 < 128u;
        const bool vy0 = (unsigned)y0 < 128u, vy1 = (unsigned)y1 < 128u;
        const bool vz0 = (unsigned)z0 < 128u, vz1 = (unsigned)z1 < 128u;
        const float v000 = (vx0 && vy0 && vz0) ? vol[(z0 * S + y0) * S + x0] : 0.0f;
        const float v001 = (vx1 && vy0 && vz0) ? vol[(z0 * S + y0) * S + x1] : 0.0f;
        const float v010 = (vx0 && vy1 && vz0) ? vol[(z0 * S + y1) * S + x0] : 0.0f;
        const float v011 = (vx1 && vy1 && vz0) ? vol[(z0 * S + y1) * S + x1] : 0.0f;
        const float v100 = (vx0 && vy0 && vz1) ? vol[(z1 * S + y0) * S + x0] : 0.0f;
        const float v101 = (vx1 && vy0 && vz1) ? vol[(z1 * S + y0) * S + x1] : 0.0f;
        const float v110 = (vx0 && vy1 && vz1) ? vol[(z1 * S + y1) * S + x0] : 0.0f;
        const float v111 = (vx1 && vy1 && vz1) ? vol[(z1 * S + y1) * S + x1] : 0.0f;
        const float c00 = v000 + fx * (v001 - v000);
        const float c01 = v010 + fx * (v011 - v010);
        const float c10 = v100 + fx * (v101 - v100);
        const float c11 = v110 + fx * (v111 - v110);
        const float c0 = c00 + fy * (c01 - c00);
        const float c1 = c10 + fy * (c11 - c10);
        acc += c0 + fz * (c1 - c0);
    }
    out[pix] = acc;
}

extern "C" void kernel_launch(void* const* d_in, const int* in_sizes, int n_in,
                              void* d_out, int out_size, void* d_ws, size_t ws_size,
                              hipStream_t stream) {
    const float* rot = (const float*)d_in[0];   // [16,3,3]
    const float* vol = (const float*)d_in[1];   // [128^3] fp32
    float* out = (float*)d_out;                 // [16*128*128]

    const size_t need3 = (size_t)3 * VOXN * sizeof(__half);  // ~15.1 MB
    const size_t need1 = (size_t)VOXN * sizeof(__half);      // ~5.03 MB

    if (ws_size >= need3) {
        __half* pv = (__half*)d_ws;
        hipMemsetAsync(out, 0, (size_t)out_size * sizeof(float), stream);
        pad_perm_kernel<<<3 * (VOXN / 256), 256, 0, stream>>>(vol, pv);
        projector_perm<3><<<4096, 256, 0, stream>>>(rot, pv, out);
    } else if (ws_size >= need1) {
        __half* pv = (__half*)d_ws;
        hipMemsetAsync(out, 0, (size_t)out_size * sizeof(float), stream);
        pad_perm_kernel<<<VOXN / 256, 256, 0, stream>>>(vol, pv);
        projector_perm<1><<<4096, 256, 0, stream>>>(rot, pv, out);
    } else {
        projector_f32<<<(16 * SS) / 256, 256, 0, stream>>>(rot, vol, out);
    }
}